// Round 1
// 7077.200 us; speedup vs baseline: 2.6267x; 2.6267x over previous
//
#include <hip/hip_runtime.h>

// Problem constants
#define VOCAB  32000
#define HIDDEN 1024
#define BATCH  8
#define SEQ    512
#define GDIM   4096   // 4*HIDDEN

typedef short bf16x8 __attribute__((ext_vector_type(8)));
typedef float f32x4  __attribute__((ext_vector_type(4)));

__device__ __forceinline__ unsigned short f2bf(float f) {
    unsigned int u = __float_as_uint(f);
    u += 0x7fff + ((u >> 16) & 1);   // RNE
    return (unsigned short)(u >> 16);
}

__device__ __forceinline__ float sigmoidf_(float x) {
    return 1.0f / (1.0f + expf(-x));
}

// ---------------------------------------------------------------------------
// f32 -> bf16 elementwise convert (n multiple of 4)
// ---------------------------------------------------------------------------
__global__ __launch_bounds__(256) void convert_bf16(const float* __restrict__ in,
                                                    unsigned short* __restrict__ out,
                                                    int n4) {
    int i = blockIdx.x * 256 + threadIdx.x;
    if (i < n4) {
        float4 v = ((const float4*)in)[i];
        ushort4 o;
        o.x = f2bf(v.x); o.y = f2bf(v.y); o.z = f2bf(v.z); o.w = f2bf(v.w);
        ((ushort4*)out)[i] = o;
    }
}

// ---------------------------------------------------------------------------
// Embedding gather: emb[(s*8+b)*H + h] = bf16(W_out[h*V + ids[b,s]])
// grid = 4096 blocks (one token each), 256 threads
// ---------------------------------------------------------------------------
__global__ __launch_bounds__(256) void gather_emb(const int* __restrict__ ids,
                                                  const float* __restrict__ W_out,
                                                  unsigned short* __restrict__ emb) {
    int r = blockIdx.x;          // r = s*8 + b
    int s = r >> 3, b = r & 7;
    int v = ids[b * SEQ + s];
    #pragma unroll
    for (int i = 0; i < 4; ++i) {
        int h = threadIdx.x + i * 256;
        emb[r * HIDDEN + h] = f2bf(W_out[(size_t)h * VOCAB + v]);
    }
}

// ---------------------------------------------------------------------------
// One-time transpose+convert: Wh [H=1024 k][4H=4096 j] f32 -> whT [4096 j][1024 k] bf16
// 32x32 tiles via LDS; coalesced reads and writes.
// grid = dim3(4096/32, 1024/32), 256 threads
// ---------------------------------------------------------------------------
__global__ __launch_bounds__(256) void transpose_wh(const float* __restrict__ Wh,
                                                    unsigned short* __restrict__ whT) {
    __shared__ unsigned short tile[32][33];
    const int j0 = blockIdx.x * 32;
    const int k0 = blockIdx.y * 32;
    const int c = threadIdx.x & 31;
    const int r = threadIdx.x >> 5;          // 0..7
    #pragma unroll
    for (int i = 0; i < 4; ++i) {
        int rr = r + i * 8;                  // k offset
        tile[rr][c] = f2bf(Wh[(size_t)(k0 + rr) * GDIM + j0 + c]);
    }
    __syncthreads();
    #pragma unroll
    for (int i = 0; i < 4; ++i) {
        int rr = r + i * 8;                  // j offset
        whT[(size_t)(j0 + rr) * HIDDEN + k0 + c] = tile[c][rr];
    }
}

// ---------------------------------------------------------------------------
// bf16 MFMA GEMM: C[M,N] = A[M,K] * B[K,N] + bias[N], fp32 out.
// 128x128 block tile, 4 waves (2x2), each wave 64x64 via 4x4 MFMA 16x16x32.
// M,N multiples of 128; K multiple of 32.
// ---------------------------------------------------------------------------
__global__ __launch_bounds__(256) void gemm_bf16_bias(
        const unsigned short* __restrict__ A,
        const unsigned short* __restrict__ B,
        const float* __restrict__ bias,
        float* __restrict__ C,
        int M, int N, int K) {
    __shared__ __attribute__((aligned(16))) unsigned short As[128 * 40];
    __shared__ __attribute__((aligned(16))) unsigned short Bs[128 * 40];

    const int tid  = threadIdx.x;
    const int lane = tid & 63;
    const int wave = tid >> 6;
    const int wm = wave >> 1, wn = wave & 1;
    const int quad = lane >> 4, r16 = lane & 15;
    const int m0 = blockIdx.y * 128, n0 = blockIdx.x * 128;

    f32x4 acc[4][4] = {};

    for (int k0 = 0; k0 < K; k0 += 32) {
        // stage A tile [128m x 32k], row-major, stride 40
        #pragma unroll
        for (int i = 0; i < 2; ++i) {
            int c = tid + 256 * i;
            int m = c >> 2, kc = (c & 3) * 8;
            uint4 v = *(const uint4*)(A + (size_t)(m0 + m) * K + k0 + kc);
            *(uint4*)(As + m * 40 + kc) = v;
        }
        // stage B tile transposed -> Bs[n][k], stride 40
        #pragma unroll
        for (int i = 0; i < 2; ++i) {
            int c = tid + 256 * i;
            int k = c >> 4, nc = (c & 15) * 8;
            uint4 v = *(const uint4*)(B + (size_t)(k0 + k) * N + n0 + nc);
            union { uint4 q; unsigned short s[8]; } u; u.q = v;
            #pragma unroll
            for (int j = 0; j < 8; ++j) Bs[(nc + j) * 40 + k] = u.s[j];
        }
        __syncthreads();

        bf16x8 af[4], bfr[4];
        #pragma unroll
        for (int mi = 0; mi < 4; ++mi)
            af[mi] = *(const bf16x8*)(As + (wm * 64 + mi * 16 + r16) * 40 + quad * 8);
        #pragma unroll
        for (int ni = 0; ni < 4; ++ni)
            bfr[ni] = *(const bf16x8*)(Bs + (wn * 64 + ni * 16 + r16) * 40 + quad * 8);

        #pragma unroll
        for (int mi = 0; mi < 4; ++mi)
            #pragma unroll
            for (int ni = 0; ni < 4; ++ni)
                acc[mi][ni] = __builtin_amdgcn_mfma_f32_16x16x32_bf16(
                    af[mi], bfr[ni], acc[mi][ni], 0, 0, 0);
        __syncthreads();
    }

    // epilogue: C/D layout col = lane&15, row = quad*4 + reg
    #pragma unroll
    for (int mi = 0; mi < 4; ++mi) {
        #pragma unroll
        for (int ni = 0; ni < 4; ++ni) {
            int col = n0 + wn * 64 + ni * 16 + r16;
            float bv = bias[col];
            #pragma unroll
            for (int r = 0; r < 4; ++r) {
                int row = m0 + wm * 64 + mi * 16 + quad * 4 + r;
                C[(size_t)row * N + col] = acc[mi][ni][r] + bv;
            }
        }
    }
}

// ---------------------------------------------------------------------------
// One LSTM timestep on the matrix pipe.
// gates[b][j] = xg[t][b][j] + sum_k h[b][k] * Wh[k][j]
// grid = 64 blocks, 256 threads (4 waves).  wave = gate g; block owns
// u in [bid*16, bid*16+16).  A = h16 [16 rows (8 batches + 8 zero)][1024] bf16,
// B-fragments read straight from whT[j][k] (L3-resident, contiguous 16B/lane).
// Fragment lane mapping identical to gemm_bf16_bias (proven on this harness):
//   A/B: row(col)=lane&15, k=quad*8 within each 32-k chunk
//   C:   col=lane&15, row=quad*4+reg
// ---------------------------------------------------------------------------
__global__ __launch_bounds__(256) void lstm_step_mfma(
        const float* __restrict__ xg,            // [SEQ*BATCH, 4H] (t-major rows)
        const unsigned short* __restrict__ whT,  // [4H, H] bf16
        const unsigned short* __restrict__ h_in, // [16, H] bf16 (rows 8..15 zero)
        unsigned short* __restrict__ h_out,      // [16, H] bf16
        float* __restrict__ c,                   // [BATCH, H] f32
        unsigned short* __restrict__ hs,         // bf16 [BATCH, SEQ, H]
        int t) {
    __shared__ float sg[4][8][16];               // [gate][batch][u]

    const int tid  = threadIdx.x;
    const int lane = tid & 63;
    const int g    = tid >> 6;                   // wave = gate
    const int r16  = lane & 15;
    const int quad = lane >> 4;
    const int u0   = blockIdx.x * 16;
    const int j0   = g * HIDDEN + u0;

    f32x4 acc = {};
    const unsigned short* ap = h_in + r16 * HIDDEN + quad * 8;
    const unsigned short* bp = whT + (size_t)(j0 + r16) * HIDDEN + quad * 8;
    #pragma unroll 16
    for (int kk = 0; kk < HIDDEN / 32; ++kk) {
        bf16x8 af = *(const bf16x8*)(ap + kk * 32);
        bf16x8 bf = *(const bf16x8*)(bp + kk * 32);
        acc = __builtin_amdgcn_mfma_f32_16x16x32_bf16(af, bf, acc, 0, 0, 0);
    }

    if (quad < 2) {
        const float* xp = xg + (size_t)(t * BATCH) * GDIM + j0 + r16;
        #pragma unroll
        for (int r = 0; r < 4; ++r) {
            int row = quad * 4 + r;              // batch
            sg[g][row][r16] = acc[r] + xp[(size_t)row * GDIM];
        }
    }
    __syncthreads();

    if (tid < 128) {
        int b = tid >> 4, ui = tid & 15, u = u0 + ui;
        float iv = sigmoidf_(sg[0][b][ui]);
        float fv = sigmoidf_(sg[1][b][ui]);
        float gv = tanhf(sg[2][b][ui]);
        float ov = sigmoidf_(sg[3][b][ui]);
        float cn = fv * c[b * HIDDEN + u] + iv * gv;
        c[b * HIDDEN + u] = cn;
        float hv = ov * tanhf(cn);
        unsigned short hb = f2bf(hv);
        h_out[b * HIDDEN + u] = hb;
        hs[((size_t)b * SEQ + t) * HIDDEN + u] = hb;
    }
}

// ---------------------------------------------------------------------------
// kernel_launch
// inputs: 0 ids[B,S] int, 1 W_out[H,V] f32, 2 b_out[V] f32,
//         3 Wx[H,4H] f32, 4 Wh[H,4H] f32, 5 b_lstm[4H] f32
// out: logits [B,S,V] f32
// ---------------------------------------------------------------------------
extern "C" void kernel_launch(void* const* d_in, const int* in_sizes, int n_in,
                              void* d_out, int out_size, void* d_ws, size_t ws_size,
                              hipStream_t stream) {
    const int*   ids    = (const int*)d_in[0];
    const float* W_out  = (const float*)d_in[1];
    const float* b_out  = (const float*)d_in[2];
    const float* Wx     = (const float*)d_in[3];
    const float* Wh     = (const float*)d_in[4];
    const float* b_lstm = (const float*)d_in[5];
    float* out = (float*)d_out;

    char* ws = (char*)d_ws;
    // workspace layout (bytes) — total 157908992 (same as previous version)
    float*          xg     = (float*)(ws + 0);                    // 512*8*4096*4  = 67108864
    unsigned short* emb    = (unsigned short*)(ws + 67108864);    // 4096*1024*2   =  8388608
    unsigned short* whT    = (unsigned short*)(ws + 67108864);    // ALIAS of emb: emb is dead
                                                                  // after gemm1; stream order
                                                                  // makes the reuse safe.
    unsigned short* wx16   = (unsigned short*)(ws + 75497472);    // 1024*4096*2   =  8388608
    unsigned short* wout16 = (unsigned short*)(ws + 83886080);    // 1024*32000*2  = 65536000
    unsigned short* hs16   = (unsigned short*)(ws + 149422080);   // 8*512*1024*2  =  8388608
    unsigned short* h16    = (unsigned short*)(ws + 157810688);   // 2*16*1024*2   =    65536
    float*          cbuf   = (float*)(ws + 157876224);            // 8*1024*4      =    32768

    // zero h ping-pong (incl. padding rows 8..15) and c in one memset
    hipMemsetAsync(h16, 0, 65536 + 32768, stream);

    // convert weights to bf16
    convert_bf16<<<(HIDDEN * GDIM / 4 + 255) / 256, 256, 0, stream>>>(Wx, wx16, HIDDEN * GDIM / 4);
    convert_bf16<<<(HIDDEN * VOCAB / 4 + 255) / 256, 256, 0, stream>>>(W_out, wout16, HIDDEN * VOCAB / 4);

    // embedding gather -> emb bf16 [S*B, H]
    gather_emb<<<SEQ * BATCH, 256, 0, stream>>>(ids, W_out, emb);

    // x_gates = emb @ Wx + b_lstm  (M=4096 rows ordered r = s*8+b)
    gemm_bf16_bias<<<dim3(GDIM / 128, SEQ * BATCH / 128), 256, 0, stream>>>(
        emb, wx16, b_lstm, xg, SEQ * BATCH, GDIM, HIDDEN);

    // Wh -> whT bf16 (overwrites emb region; emb no longer needed)
    transpose_wh<<<dim3(GDIM / 32, HIDDEN / 32), 256, 0, stream>>>(Wh, whT);

    // sequential scan on the matrix pipe
    for (int t = 0; t < SEQ; ++t) {
        const unsigned short* hin = h16 + (t & 1) * (16 * HIDDEN);
        unsigned short* hout      = h16 + ((t + 1) & 1) * (16 * HIDDEN);
        lstm_step_mfma<<<HIDDEN / 16, 256, 0, stream>>>(xg, whT, hin, hout, cbuf, hs16, t);
    }

    // logits = hs @ W_out + b_out  (hs rows ordered r = b*512+s -> matches out)
    gemm_bf16_bias<<<dim3(VOCAB / 128, SEQ * BATCH / 128), 256, 0, stream>>>(
        hs16, wout16, b_out, out, SEQ * BATCH, VOCAB, HIDDEN);
}